// Round 14
// baseline (246.763 us; speedup 1.0000x reference)
//
#include <hip/hip_runtime.h>
#include <math.h>

#define B_   32
#define N_   128
#define H_   100
#define ROWS (B_ * N_)    // 4096
#define RH   (ROWS * H_)  // 409600
#define OUTSZ (B_ * H_)   // 3200

// ---------------------------------------------------------------------------
// K1: hv = nodes@Wv, hw = nodes@Ww. 2 rows per 256-thread block; lane j = h.
// Also zero-initializes out (poisoned 0xAA before every timed call).
__global__ __launch_bounds__(256, 6) void k_proj0(const float* __restrict__ nodes,
                                                  const float* __restrict__ Wv,
                                                  const float* __restrict__ Ww,
                                                  float* __restrict__ hv,
                                                  float* __restrict__ hw,
                                                  float* __restrict__ out) {
    __shared__ float nod_s[2][H_];
    const int row0 = blockIdx.x * 2;
    const int t = threadIdx.x, r = t >> 7, j = t & 127;
    {   // zero out[] (3 dispatches before any atomicAdd; stream-ordered)
        const int gid = blockIdx.x * 256 + t;
        if (gid < OUTSZ) out[gid] = 0.f;
    }
    {
        const float4* ng = (const float4*)(nodes + (size_t)row0 * H_);
        if (t < 50) ((float4*)nod_s)[t] = ng[t];
    }
    __syncthreads();
    if (j >= H_) return;
    const float4* h4p = (const float4*)nod_s[r];
    float va = 0.f, wa = 0.f;
#pragma unroll 5
    for (int k4 = 0; k4 < 25; ++k4) {
        const float4 h4 = h4p[k4];
        const int k = k4 * 4;
        va = fmaf(h4.x, Wv[(k + 0) * H_ + j], va);
        wa = fmaf(h4.x, Ww[(k + 0) * H_ + j], wa);
        va = fmaf(h4.y, Wv[(k + 1) * H_ + j], va);
        wa = fmaf(h4.y, Ww[(k + 1) * H_ + j], wa);
        va = fmaf(h4.z, Wv[(k + 2) * H_ + j], va);
        wa = fmaf(h4.z, Ww[(k + 2) * H_ + j], wa);
        va = fmaf(h4.w, Wv[(k + 3) * H_ + j], va);
        wa = fmaf(h4.w, Ww[(k + 3) * H_ + j], wa);
    }
    hv[(size_t)(row0 + r) * H_ + j] = va;
    hw[(size_t)(row0 + r) * H_ + j] = wa;
}

// ---------------------------------------------------------------------------
// K2: one fused message pass. 2 rows per 256-thread block. MESSAGE phase is
// w-split with REGISTER-RESIDENT edges: wave wv serves (row wv>>1, w-half
// wv&1); at stage time lane l loads the edge float4 for w=(wv&1)*64+l — the
// message loop broadcasts it via v_readlane (literal w, full unroll): ZERO
// LDS in the message loop. Edge mask = the wave's own stage __ballot (SGPR).
// hw read as coalesced float2. Partials combined via msgp_s. UPDATE/PROJ/
// READOUT phases r13-verbatim (r = t>>7, j = t&127).
__global__ __launch_bounds__(256, 8) void k_pass(const float* __restrict__ edges,
                                                 const float* __restrict__ We,
                                                 const float* __restrict__ Wu,
                                                 const float* __restrict__ Wv,
                                                 const float* __restrict__ Ww,
                                                 const float* __restrict__ Wr,
                                                 const float* __restrict__ nodes,
                                                 float* __restrict__ hv_io,
                                                 const float* __restrict__ hw_in,
                                                 float* __restrict__ hw_out,
                                                 const float* __restrict__ hid_in,
                                                 float* __restrict__ hidden,
                                                 float* __restrict__ out,
                                                 int mode) {
    __shared__ float  asum_part[4];    // per-wave partial row sums
    __shared__ float  msgp_s[4][H_];   // per-wave partial messages
    __shared__ float  hid_s[2][H_];
    __shared__ float  msg_s[2][H_];
    __shared__ float  hn_s[2][H_];
    __shared__ float  nod_s[2][H_];    // mode 2 only
    __shared__ float  red_s[2][H_];    // mode 2 only

    const int row0 = blockIdx.x * 2;
    const int b = row0 >> 7;
    const int t = threadIdx.x, r = t >> 7, j = t & 127;
    const int wv = t >> 6, l = t & 63;
    const int row = row0 + r;
    const bool act = (j < H_);

    // ---- stage: edges into REGISTERS (lane l holds (row wv>>1, w (wv&1)*64+l));
    //      ballot -> SGPR edge mask; shuffle-reduce -> asum; hid (+nodes) to LDS
    const float4* eg = (const float4*)(edges + (size_t)row0 * N_ * 4);
    const float4 emy = eg[t];                     // coalesced; stays in VGPRs
    unsigned long long bal;
    {
        float s = (emy.x + emy.y) + (emy.z + emy.w);
        bal = __ballot(s != 0.f);                 // wave-uniform SGPR mask
#pragma unroll
        for (int off = 32; off > 0; off >>= 1) s += __shfl_down(s, off);
        if (l == 0) asum_part[wv] = s;
    }
    {
        const float4* hg = (const float4*)(hid_in + (size_t)row0 * H_);
        if (t < 50) ((float4*)hid_s)[t] = hg[t];
        if (mode == 2) {
            const float4* ng = (const float4*)(nodes + (size_t)row0 * H_);
            if (t < 50) ((float4*)nod_s)[t] = ng[t];
        }
    }
    __syncthreads();

    // ---- message phase (w-split, zero LDS) ----
    {
        const int mrow = row0 + (wv >> 1);
        const int w0 = (wv & 1) * 64;
        const int ll = (l < 50) ? l : 49;         // clamp keeps loads in-bounds
        const float2 hv2 = *(const float2*)(hv_io + (size_t)mrow * H_ + 2 * ll);
        const float2 we0 = *(const float2*)(We + 0 * H_ + 2 * ll);
        const float2 we1 = *(const float2*)(We + 1 * H_ + 2 * ll);
        const float2 we2 = *(const float2*)(We + 2 * H_ + 2 * ll);
        const float2 we3 = *(const float2*)(We + 3 * H_ + 2 * ll);
        const float* hwbase = hw_in + ((size_t)b * N_ + w0) * H_ + 2 * ll;
        const int exi = __float_as_int(emy.x);
        const int eyi = __float_as_int(emy.y);
        const int ezi = __float_as_int(emy.z);
        const int ewi = __float_as_int(emy.w);
        float acc0 = 0.f, acc1 = 0.f;
#pragma unroll
        for (int w = 0; w < 64; ++w) {            // literal w -> v_readlane
            const float ex = __int_as_float(__builtin_amdgcn_readlane(exi, w));
            const float ey = __int_as_float(__builtin_amdgcn_readlane(eyi, w));
            const float ez = __int_as_float(__builtin_amdgcn_readlane(ezi, w));
            const float ew = __int_as_float(__builtin_amdgcn_readlane(ewi, w));
            const float2 hw2 = *(const float2*)(hwbase + (size_t)w * H_);
            const float m = ((bal >> w) & 1ull) ? 1.f : 0.f;   // SALU bit
            float p0 = hv2.x + hw2.x, p1 = hv2.y + hw2.y;
            p0 = fmaf(ex, we0.x, p0); p1 = fmaf(ex, we0.y, p1);
            p0 = fmaf(ey, we1.x, p0); p1 = fmaf(ey, we1.y, p1);
            p0 = fmaf(ez, we2.x, p0); p1 = fmaf(ez, we2.y, p1);
            p0 = fmaf(ew, we3.x, p0); p1 = fmaf(ew, we3.y, p1);
            acc0 = fmaf(m, fmaxf(p0, 0.f), acc0);
            acc1 = fmaf(m, fmaxf(p1, 0.f), acc1);
        }
        if (l < 50) *(float2*)(&msgp_s[wv][2 * l]) = make_float2(acc0, acc1);
    }
    __syncthreads();

    // combine w-half partials into msg (r/j mapping)
    if (act) msg_s[r][j] = msgp_s[2 * r][j] + msgp_s[2 * r + 1][j];
    __syncthreads();

    const float nm = ((asum_part[2 * r] + asum_part[2 * r + 1]) != 0.f) ? 1.f : 0.f;

    if (act) {
        const float4* h4p = (const float4*)hid_s[r];
        const float4* m4p = (const float4*)msg_s[r];
        float u = 0.f;
#pragma unroll 5
        for (int k4 = 0; k4 < 25; ++k4) {
            const float4 h4 = h4p[k4];
            const int k = k4 * 4;
            u = fmaf(h4.x, Wu[(k + 0) * H_ + j], u);
            u = fmaf(h4.y, Wu[(k + 1) * H_ + j], u);
            u = fmaf(h4.z, Wu[(k + 2) * H_ + j], u);
            u = fmaf(h4.w, Wu[(k + 3) * H_ + j], u);
        }
#pragma unroll 5
        for (int k4 = 0; k4 < 25; ++k4) {
            const float4 m4 = m4p[k4];
            const int k = H_ + k4 * 4;
            u = fmaf(m4.x, Wu[(k + 0) * H_ + j], u);
            u = fmaf(m4.y, Wu[(k + 1) * H_ + j], u);
            u = fmaf(m4.z, Wu[(k + 2) * H_ + j], u);
            u = fmaf(m4.w, Wu[(k + 3) * H_ + j], u);
        }
        const float nh = (nm != 0.f) ? tanhf(u) : hid_s[r][j];
        hn_s[r][j] = nh;
        if (mode == 1) hidden[(size_t)row * H_ + j] = nh;
    }
    __syncthreads();

    if (mode == 1) {        // next pass's hv/hw from fresh hidden (own rows)
        if (act) {
            const float4* h4p = (const float4*)hn_s[r];
            float va = 0.f, wa = 0.f;
#pragma unroll 5
            for (int k4 = 0; k4 < 25; ++k4) {
                const float4 h4 = h4p[k4];
                const int k = k4 * 4;
                va = fmaf(h4.x, Wv[(k + 0) * H_ + j], va);
                wa = fmaf(h4.x, Ww[(k + 0) * H_ + j], wa);
                va = fmaf(h4.y, Wv[(k + 1) * H_ + j], va);
                wa = fmaf(h4.y, Ww[(k + 1) * H_ + j], wa);
                va = fmaf(h4.z, Wv[(k + 2) * H_ + j], va);
                wa = fmaf(h4.z, Ww[(k + 2) * H_ + j], wa);
                va = fmaf(h4.w, Wv[(k + 3) * H_ + j], va);
                wa = fmaf(h4.w, Ww[(k + 3) * H_ + j], wa);
            }
            hv_io[(size_t)row * H_ + j] = va;     // row-local: safe in-place
            hw_out[(size_t)row * H_ + j] = wa;    // double-buffered
        }
    } else {                // mode 2: fused readout
        if (act) {
            const float4* h4p = (const float4*)hn_s[r];
            const float4* n4p = (const float4*)nod_s[r];
            float u = 0.f;
#pragma unroll 5
            for (int k4 = 0; k4 < 25; ++k4) {
                const float4 h4 = h4p[k4];
                const int k = k4 * 4;
                u = fmaf(h4.x, Wr[(k + 0) * H_ + j], u);
                u = fmaf(h4.y, Wr[(k + 1) * H_ + j], u);
                u = fmaf(h4.z, Wr[(k + 2) * H_ + j], u);
                u = fmaf(h4.w, Wr[(k + 3) * H_ + j], u);
            }
#pragma unroll 5
            for (int k4 = 0; k4 < 25; ++k4) {
                const float4 n4 = n4p[k4];
                const int k = H_ + k4 * 4;
                u = fmaf(n4.x, Wr[(k + 0) * H_ + j], u);
                u = fmaf(n4.y, Wr[(k + 1) * H_ + j], u);
                u = fmaf(n4.z, Wr[(k + 2) * H_ + j], u);
                u = fmaf(n4.w, Wr[(k + 3) * H_ + j], u);
            }
            red_s[r][j] = nm * fmaxf(u, 0.f);
        }
        __syncthreads();
        if (t < H_) atomicAdd(out + b * H_ + t, red_s[0][t] + red_s[1][t]);
    }
}

// ---------------------------------------------------------------------------
extern "C" void kernel_launch(void* const* d_in, const int* in_sizes, int n_in,
                              void* d_out, int out_size, void* d_ws, size_t ws_size,
                              hipStream_t stream) {
    const float* nodes = (const float*)d_in[0];
    const float* edges = (const float*)d_in[1];
    const float* Wv    = (const float*)d_in[2];
    const float* Ww    = (const float*)d_in[3];
    const float* We    = (const float*)d_in[4];
    const float* Wu    = (const float*)d_in[5];
    const float* Wr    = (const float*)d_in[6];
    float* out = (float*)d_out;

    float* hidden = (float*)d_ws;     // RH
    float* hv     = hidden + RH;      // RH
    float* hwA    = hv + RH;          // RH
    float* hwB    = hwA + RH;         // RH

    k_proj0<<<ROWS / 2, 256, 0, stream>>>(nodes, Wv, Ww, hv, hwA, out);

    k_pass<<<ROWS / 2, 256, 0, stream>>>(edges, We, Wu, Wv, Ww, Wr, nodes,
                                         hv, hwA, hwB, nodes, hidden, out, 1);
    k_pass<<<ROWS / 2, 256, 0, stream>>>(edges, We, Wu, Wv, Ww, Wr, nodes,
                                         hv, hwB, hwA, hidden, hidden, out, 1);
    k_pass<<<ROWS / 2, 256, 0, stream>>>(edges, We, Wu, Wv, Ww, Wr, nodes,
                                         hv, hwA, hwB, hidden, hidden, out, 2);
}